// Round 1
// baseline (410.348 us; speedup 1.0000x reference)
//
#include <hip/hip_runtime.h>
#include <hip/hip_bf16.h>

#define QL 1024
#define KL 1024
#define HM 64
#define DD 128
#define SM_SCALE 0.08838834764831845f

#define BM 128
#define BN 128
#define LDPAD 136   // 128 + 8 bf16 pad -> 272B row stride, 2-way bank alias (free)

typedef __bf16 bf16x8 __attribute__((ext_vector_type(8)));
typedef __bf16 bf16x4 __attribute__((ext_vector_type(4)));
typedef float floatx4 __attribute__((ext_vector_type(4)));

// Batched QK^T: C[g][q][k] = sum_d Q[q][g][d] * K[k][g][d], then *scale + mask
// out[g][q][k] for k in [0,1024); row stride 1025 (sink col written separately)
__global__ __launch_bounds__(256, 2)
void qk_kernel(const float* __restrict__ Qg, const float* __restrict__ Kg,
               const float* __restrict__ mask, float* __restrict__ out)
{
    const int g    = blockIdx.y;        // hm batch 0..63
    const int tile = blockIdx.x;        // 0..63
    const int qt = (tile >> 3) * BM;
    const int kt = (tile & 7) * BN;

    __shared__ __bf16 As[BM][LDPAD];
    __shared__ __bf16 Bs[BN][LDPAD];

    const int t = threadIdx.x;

    // ---- stage: global fp32 -> bf16 -> LDS (128 rows x 32 float4 each) ----
    const float* Ag = Qg + (size_t)qt * (HM * DD) + (size_t)g * DD;
    const float* Bg = Kg + (size_t)kt * (HM * DD) + (size_t)g * DD;
#pragma unroll
    for (int j = 0; j < 16; ++j) {
        int c = t + 256 * j;          // flat float4 chunk 0..4095
        int row = c >> 5;             // 0..127
        int c4  = c & 31;             // float4 col 0..31
        float4 a = *(const float4*)(Ag + (size_t)row * (HM * DD) + c4 * 4);
        float4 b = *(const float4*)(Bg + (size_t)row * (HM * DD) + c4 * 4);
        bf16x4 av = { (__bf16)a.x, (__bf16)a.y, (__bf16)a.z, (__bf16)a.w };
        bf16x4 bv = { (__bf16)b.x, (__bf16)b.y, (__bf16)b.z, (__bf16)b.w };
        *(bf16x4*)&As[row][c4 * 4] = av;
        *(bf16x4*)&Bs[row][c4 * 4] = bv;
    }
    __syncthreads();

    // ---- compute: 4 waves, each 64x64, 4x4 tiles of 16x16x32 MFMA ----
    const int wave = t >> 6;
    const int lane = t & 63;
    const int wm = (wave & 1) * 64;
    const int wn = (wave >> 1) * 64;
    const int lr = lane & 15;
    const int quad = lane >> 4;

    floatx4 acc[4][4] = {};

#pragma unroll
    for (int ks = 0; ks < 4; ++ks) {
        const int d0 = ks * 32 + quad * 8;
        bf16x8 af[4], bf[4];
#pragma unroll
        for (int mi = 0; mi < 4; ++mi)
            af[mi] = *(const bf16x8*)&As[wm + mi * 16 + lr][d0];
#pragma unroll
        for (int ni = 0; ni < 4; ++ni)
            bf[ni] = *(const bf16x8*)&Bs[wn + ni * 16 + lr][d0];
#pragma unroll
        for (int mi = 0; mi < 4; ++mi)
#pragma unroll
            for (int ni = 0; ni < 4; ++ni)
                acc[mi][ni] = __builtin_amdgcn_mfma_f32_16x16x32_bf16(
                    af[mi], bf[ni], acc[mi][ni], 0, 0, 0);
    }

    // ---- epilogue: C/D layout col=lane&15 (k), row=quad*4+r (q) ----
    const size_t obase = (size_t)g * QL * 1025;
#pragma unroll
    for (int mi = 0; mi < 4; ++mi) {
#pragma unroll
        for (int r = 0; r < 4; ++r) {
            int q = qt + wm + mi * 16 + quad * 4 + r;
            const float* mrow = mask + (size_t)q * KL;
            float* orow = out + obase + (size_t)q * 1025;
#pragma unroll
            for (int ni = 0; ni < 4; ++ni) {
                int k = kt + wn + ni * 16 + lr;
                orow[k] = acc[mi][ni][r] * SM_SCALE + mrow[k];
            }
        }
    }
}

// out[g][q][1024] = sinks[g][q]
__global__ void sink_kernel(const float* __restrict__ sinks, float* __restrict__ out)
{
    int idx = blockIdx.x * 256 + threadIdx.x;   // 0..65535 = g*1024+q
    out[(size_t)idx * 1025 + 1024] = sinks[idx];
}

extern "C" void kernel_launch(void* const* d_in, const int* in_sizes, int n_in,
                              void* d_out, int out_size, void* d_ws, size_t ws_size,
                              hipStream_t stream)
{
    const float* Q     = (const float*)d_in[0];
    const float* K     = (const float*)d_in[1];
    const float* mask  = (const float*)d_in[2];
    const float* sinks = (const float*)d_in[3];
    float* out = (float*)d_out;

    sink_kernel<<<(HM * QL) / 256, 256, 0, stream>>>(sinks, out);
    qk_kernel<<<dim3(64, 64), 256, 0, stream>>>(Q, K, mask, out);
}